// Round 12
// baseline (268.103 us; speedup 1.0000x reference)
//
#include <hip/hip_runtime.h>
#include <hip/hip_bf16.h>

// Supervised contrastive loss, B=8192, D=256, T=0.07, 100 classes.
//   memset: zero sn+cls_cnt+gacc (one ~34KB hipMemsetAsync)
//   prep:   z f32 -> bf16 FRAGMENT-MAJOR zbf2 (1KB per (16-row-tile, kf)
//           fragment unit, lane slot = (c5&3)*16 + (row&15)) + bucketing.
//   passA:  row sums of exp(z@z^T/T), diagonal INCLUDED (cancels in passB
//           bitwise -- same bf16 frags, same MFMA order). No LDS, no
//           barriers. 512 blocks = 16 row-blocks(512) x 32 col-chunks(256).
//           4 waves/block; each wave: 128 rows in regs (a[8][8], 128 VGPR),
//           streams 16 col-tiles with reg-dbuf b loads (coalesced dwordx4
//           from L2-resident zbf2). 8 indep MFMA chains. launch_bounds
//           (256,2) -> 256-VGPR cap, ~235 used, 2 waves/SIMD.
//           Per-row fire-and-forget atomicAdd into sn.
//   passB:  per class, grid (100,2) mi-interleaved split, 8 waves: gather
//           members from f32 z (same f2bf bits), pass1 all-pairs MFMA
//           (diag INCLUDED -> sum_same cancels passA's diag) + e-cache in
//           LDS dmat; pass2 log1p from dmat (self excluded); atomics->gacc.
//   final:  out = gacc[0]/max(gacc[1],1)

#define BN 8192
#define DD 256
#define INV_T (1.0f / 0.07f)
#define CAPI 256
#define CAP 160
#define IPAD 164

typedef __attribute__((ext_vector_type(8))) __bf16 bf16x8;
typedef __attribute__((ext_vector_type(4))) float f32x4;

static __device__ __forceinline__ unsigned short f2bf(float f) {
    unsigned int u = __builtin_bit_cast(unsigned int, f);
    u = (u + 0x7FFFu + ((u >> 16) & 1u)) >> 16;   // RNE, inputs finite
    return (unsigned short)u;
}
static __device__ __forceinline__ float bf2f(unsigned short s) {
    unsigned int u = (unsigned int)s << 16;
    return __builtin_bit_cast(float, u);
}

// ------- kernel 1: f32 -> bf16 fragment-major zbf2 + class bucketing ------
__global__ __launch_bounds__(256) void k_prep(const float* __restrict__ z,
                                              unsigned short* __restrict__ zbf2,
                                              const int* __restrict__ labels,
                                              int* __restrict__ cls_cnt,
                                              int* __restrict__ cls_idx) {
    const int gid = blockIdx.x * 256 + threadIdx.x;       // 262144 threads
    const float4* z4 = (const float4*)z;
    float4 v0 = z4[gid * 2 + 0];
    float4 v1 = z4[gid * 2 + 1];
    unsigned short r[8];
    r[0] = f2bf(v0.x); r[1] = f2bf(v0.y); r[2] = f2bf(v0.z); r[3] = f2bf(v0.w);
    r[4] = f2bf(v1.x); r[5] = f2bf(v1.y); r[6] = f2bf(v1.z); r[7] = f2bf(v1.w);
    const int j = gid >> 5, c5 = gid & 31;
    const int idx16 = (((j >> 4) * 8 + (c5 >> 2)) * 64) + (c5 & 3) * 16 + (j & 15);
    ((uint4*)zbf2)[idx16] = *(const uint4*)r;
    if (gid < BN) {                                       // cls_cnt pre-zeroed
        const int c = labels[gid];
        const int slot = atomicAdd(&cls_cnt[c], 1);
        if (slot < CAPI) cls_idx[c * CAPI + slot] = gid;
    }
}

// ---------------- kernel 2: row sums of exp(z z^T / T), diag included -----
// Grid 512 = 16 row-blocks x 32 col-chunks. 256 thr = 4 waves.
// Wave: 128 rows (a[8][8] regs) x 16 streamed col-tiles (reg-dbuf).
__global__ __launch_bounds__(256, 2) void k_passA(const char* __restrict__ zb2,
                                                  float* __restrict__ sn) {
    const int tid = threadIdx.x;
    const int w = tid >> 6, lane = tid & 63;
    const int l15 = lane & 15, lk = lane >> 4;
    const int rowblk = blockIdx.x >> 5;       // 16 row-blocks of 512
    const int cchunk = blockIdx.x & 31;       // 32 chunks of 256 cols
    const int rowwave = rowblk * 512 + w * 128;
    const int jt0 = cchunk * 16;              // first 16-col tile index

    // A: this wave's 128 rows, full K, fragment-major (one dwordx4 per frag)
    const int rt0 = rowwave >> 4;
    bf16x8 a[8][8];
#pragma unroll
    for (int m = 0; m < 8; ++m) {
        const char* p = zb2 + ((size_t)(rt0 + m) * 8192) + lane * 16;
#pragma unroll
        for (int kf = 0; kf < 8; ++kf)
            a[m][kf] = *(const bf16x8*)(p + kf * 1024);
    }

    float snp[8][4] = {};
    bf16x8 b0[8], b1[8];

    auto loadB = [&](bf16x8 (&dst)[8], int jt) {
        const char* p = zb2 + ((size_t)jt * 8192) + lane * 16;
#pragma unroll
        for (int kf = 0; kf < 8; ++kf)
            dst[kf] = *(const bf16x8*)(p + kf * 1024);
    };
    auto computeTile = [&](bf16x8 (&bx)[8]) {
        f32x4 acc[8];
#pragma unroll
        for (int m = 0; m < 8; ++m) acc[m] = (f32x4){0.f, 0.f, 0.f, 0.f};
#pragma unroll
        for (int kf = 0; kf < 8; ++kf)
#pragma unroll
            for (int m = 0; m < 8; ++m)   // 8 independent MFMA chains
                acc[m] = __builtin_amdgcn_mfma_f32_16x16x32_bf16(a[m][kf], bx[kf], acc[m], 0, 0, 0);
#pragma unroll
        for (int m = 0; m < 8; ++m)
#pragma unroll
            for (int rr = 0; rr < 4; ++rr)
                snp[m][rr] += __expf(acc[m][rr] * INV_T);   // diag included
    };

    loadB(b0, jt0);
    for (int t = 0; t < 16; t += 2) {
        loadB(b1, jt0 + t + 1);
        computeTile(b0);
        if (t + 2 < 16) loadB(b0, jt0 + t + 2);
        computeTile(b1);
    }

    // reduce across the 16 l15 lanes sharing each row; one atomic per row
#pragma unroll
    for (int m = 0; m < 8; ++m) {
#pragma unroll
        for (int rr = 0; rr < 4; ++rr) {
            float v = snp[m][rr];
            v += __shfl_xor(v, 1, 64);
            v += __shfl_xor(v, 2, 64);
            v += __shfl_xor(v, 4, 64);
            v += __shfl_xor(v, 8, 64);
            if (l15 == 0)
                atomicAdd(&sn[rowwave + m * 16 + lk * 4 + rr], v);
        }
    }
}

// ---------------- kernel 3: per-class positive pairs ----------------------
// Grid (100,2) x 512 thr (8 waves); block y owns mi rows with mi%2==y.
__global__ __launch_bounds__(512) void k_passB(const float* __restrict__ zf,
                                               const float* __restrict__ sn,
                                               const int* __restrict__ cls_cnt,
                                               const int* __restrict__ cls_idx,
                                               float* __restrict__ gacc) {
    __shared__ char Zc[CAP * 512];             // swizzled [row][512 B]
    __shared__ unsigned short dmat[CAP * IPAD];// col-major e cache [j][iPad]
    __shared__ int glist[CAP];
    __shared__ float snl[CAP];
    __shared__ float sums[CAP];
    __shared__ float blkL;

    const int c = blockIdx.x;
    const int y = blockIdx.y;
    const int tid = threadIdx.x;
    const int w = tid >> 6, lane = tid & 63;
    const int l15 = lane & 15, lk = lane >> 4;

    const int n_c = min(cls_cnt[c], CAP);
    const int nt = (n_c + 15) >> 4;
    const int rows_p = nt * 16;

    if (tid < CAP) glist[tid] = (tid < n_c) ? cls_idx[c * CAPI + tid] : 0;
    if (tid == 0) blkL = 0.f;
    __syncthreads();

    // gather: 32 lanes per row; read f32, convert (bitwise == zbf2 bits)
    for (int e2 = w * 2; e2 < rows_p; e2 += 16) {
        const int row = e2 + (lane >> 5);
        const int li = lane & 31;
        const float* src = zf + (size_t)glist[row] * DD + li * 8;
        float4 v0 = *(const float4*)(src);
        float4 v1 = *(const float4*)(src + 4);
        unsigned short r[8];
        r[0] = f2bf(v0.x); r[1] = f2bf(v0.y); r[2] = f2bf(v0.z); r[3] = f2bf(v0.w);
        r[4] = f2bf(v1.x); r[5] = f2bf(v1.y); r[6] = f2bf(v1.z); r[7] = f2bf(v1.w);
        *(uint4*)(Zc + row * 512 + ((li * 16) ^ ((row & 7) << 4))) = *(const uint4*)r;
    }
    __syncthreads();

    // ---- pass 1: sum_same (diag INCLUDED -> cancels passA's diag) ----
    for (int mi = 2 * w + y; mi < nt; mi += 16) {
        const int rowA = mi * 16 + l15;
        const int swa = (rowA & 7) << 4;
        bf16x8 a[8];
#pragma unroll
        for (int kf = 0; kf < 8; ++kf)
            a[kf] = *(const bf16x8*)(Zc + rowA * 512 + ((lk * 16 + kf * 64) ^ swa));
        float sp[4] = {};
        for (int nj = 0; nj < nt; ++nj) {
            const int colB = nj * 16 + l15;
            const int swb = (colB & 7) << 4;
            bf16x8 b[8];
#pragma unroll
            for (int kf = 0; kf < 8; ++kf)
                b[kf] = *(const bf16x8*)(Zc + colB * 512 + ((lk * 16 + kf * 64) ^ swb));
            f32x4 acc = {};
#pragma unroll
            for (int kf = 0; kf < 8; ++kf)
                acc = __builtin_amdgcn_mfma_f32_16x16x32_bf16(a[kf], b[kf], acc, 0, 0, 0);
            unsigned short ep[4];
#pragma unroll
            for (int rr = 0; rr < 4; ++rr) {
                const float e = __expf(acc[rr] * INV_T);
                ep[rr] = f2bf(e);
                sp[rr] += (colB < n_c) ? e : 0.f;
            }
            uint2 uv;
            uv.x = (unsigned)ep[0] | ((unsigned)ep[1] << 16);
            uv.y = (unsigned)ep[2] | ((unsigned)ep[3] << 16);
            *(uint2*)&dmat[colB * IPAD + mi * 16 + lk * 4] = uv;
        }
#pragma unroll
        for (int rr = 0; rr < 4; ++rr) {
            float v = sp[rr];
            v += __shfl_xor(v, 1, 64);
            v += __shfl_xor(v, 2, 64);
            v += __shfl_xor(v, 4, 64);
            v += __shfl_xor(v, 8, 64);
            if (l15 == 0) sums[mi * 16 + lk * 4 + rr] = v;
        }
    }
    __syncthreads();
    if (tid < CAP)
        snl[tid] = (tid < n_c) ? (sn[glist[tid]] - sums[tid]) : 0.f;
    __syncthreads();

    // ---- pass 2: pair losses from the e-cache (self excluded) ----
    for (int mi = 2 * w + y; mi < nt; mi += 16) {
        float sneg[4];
#pragma unroll
        for (int rr = 0; rr < 4; ++rr) {
            const int i = mi * 16 + lk * 4 + rr;
            sneg[rr] = (i < n_c) ? snl[i] : 0.f;
        }
        float sp[4] = {};
        for (int nj = 0; nj < nt; ++nj) {
            const int colB = nj * 16 + l15;
            const uint2 pk = *(const uint2*)&dmat[colB * IPAD + mi * 16 + lk * 4];
            float ev[4];
            ev[0] = bf2f((unsigned short)(pk.x & 0xffff));
            ev[1] = bf2f((unsigned short)(pk.x >> 16));
            ev[2] = bf2f((unsigned short)(pk.y & 0xffff));
            ev[3] = bf2f((unsigned short)(pk.y >> 16));
#pragma unroll
            for (int rr = 0; rr < 4; ++rr) {
                const int i = mi * 16 + lk * 4 + rr;
                const float t = log1pf(sneg[rr] / ev[rr]);
                sp[rr] += (colB < n_c && i != colB) ? t : 0.f;
            }
        }
#pragma unroll
        for (int rr = 0; rr < 4; ++rr) {
            float v = sp[rr];
            v += __shfl_xor(v, 1, 64);
            v += __shfl_xor(v, 2, 64);
            v += __shfl_xor(v, 4, 64);
            v += __shfl_xor(v, 8, 64);
            const int i = mi * 16 + lk * 4 + rr;
            if (l15 == 0 && i < n_c && n_c > 1)
                atomicAdd(&blkL, v / (float)(n_c - 1));
        }
    }
    __syncthreads();
    if (tid == 0 && n_c > 1) {
        atomicAdd(&gacc[0], blkL);
        if (y == 0) atomicAdd(&gacc[1], (float)n_c);
    }
}

// ---------------- kernel 4: final scalar ----------------------------------
__global__ void k_final(const float* __restrict__ gacc, float* __restrict__ out) {
    if (threadIdx.x == 0) {
        const float L = gacc[0], V = gacc[1];
        out[0] = (V > 0.f) ? L / fmaxf(V, 1.f) : 0.f;
    }
}

extern "C" void kernel_launch(void* const* d_in, const int* in_sizes, int n_in,
                              void* d_out, int out_size, void* d_ws, size_t ws_size,
                              hipStream_t stream) {
    const float* z      = (const float*)d_in[0];
    const int*   labels = (const int*)d_in[1];
    float* out = (float*)d_out;

    char* ws = (char*)d_ws;
    // zbf2 4MB | sn 32KB | cls_cnt 1KB | gacc 8B | cls_idx 100KB
    unsigned short* zbf2 = (unsigned short*)ws;
    size_t off = (size_t)BN * DD * sizeof(unsigned short);
    float* sn      = (float*)(ws + off);  off += BN * sizeof(float);
    int*   cls_cnt = (int*)(ws + off);    off += 1024;
    float* gacc    = (float*)(ws + off);  off += 8;
    int*   cls_idx = (int*)(ws + off);    off += 100 * CAPI * sizeof(int);

    hipMemsetAsync(sn, 0, BN * sizeof(float) + 1024 + 8, stream);
    k_prep  <<<1024, 256, 0, stream>>>(z, zbf2, labels, cls_cnt, cls_idx);
    k_passA <<<512, 256, 0, stream>>>((const char*)zbf2, sn);
    k_passB <<<dim3(100, 2), 512, 0, stream>>>(z, sn, cls_cnt, cls_idx, gacc);
    k_final <<<1, 64, 0, stream>>>(gacc, out);
}

// Round 13
// 103.518 us; speedup vs baseline: 2.5899x; 2.5899x over previous
//
#include <hip/hip_runtime.h>
#include <hip/hip_bf16.h>

// Supervised contrastive loss, B=8192, D=256, T=0.07, 100 classes.
//   memset: zero sn/cls_cnt/gacc/sums_g (one ~98KB hipMemsetAsync)
//   prep:   z f32 -> bf16 FRAGMENT-MAJOR zbf2 + class bucketing.
//   gather: per-class bf16 row-major zcls (zero-padded to 16-row tiles).
//   passB1: grid (100,10): block (c,t) = 16 rows x all class cols: MFMA
//           (bitwise == passA via identical frags+order+exp2f), e-cache to
//           global emat (bf16), row sums_g via atomics. Runs BEFORE passA
//           (independent), ~1000 small blocks = good occupancy.
//   passA:  row sums of exp(z@z^T/T), diag masked. R11 structure (best
//           measured): no LDS, no barriers; 512 blocks = 128 row-tiles(64)
//           x 4 col-quarters, 8 waves; a[4][8] regs; reg-dbuf b loads from
//           L2-resident fragment-major zbf2. Fire-and-forget sn atomics.
//   passB2: grid (100,10): sneg = sn - sums_g; pair losses from emat;
//           atomics into gacc.
//   final:  out = gacc[0]/max(gacc[1],1)

#define BN 8192
#define DD 256
#define K2E 20.609929155556628f   // (1/0.07) * log2(e)
#define CAPI 256
#define CAP 160

typedef __attribute__((ext_vector_type(8))) __bf16 bf16x8;
typedef __attribute__((ext_vector_type(4))) float f32x4;

static __device__ __forceinline__ unsigned short f2bf(float f) {
    unsigned int u = __builtin_bit_cast(unsigned int, f);
    u = (u + 0x7FFFu + ((u >> 16) & 1u)) >> 16;   // RNE, inputs finite
    return (unsigned short)u;
}
static __device__ __forceinline__ float bf2f(unsigned short s) {
    unsigned int u = (unsigned int)s << 16;
    return __builtin_bit_cast(float, u);
}

// ------- kernel 1: f32 -> bf16 fragment-major zbf2 + class bucketing ------
__global__ __launch_bounds__(256) void k_prep(const float* __restrict__ z,
                                              unsigned short* __restrict__ zbf2,
                                              const int* __restrict__ labels,
                                              int* __restrict__ cls_cnt,
                                              int* __restrict__ cls_idx) {
    const int gid = blockIdx.x * 256 + threadIdx.x;       // 262144 threads
    const float4* z4 = (const float4*)z;
    float4 v0 = z4[gid * 2 + 0];
    float4 v1 = z4[gid * 2 + 1];
    unsigned short r[8];
    r[0] = f2bf(v0.x); r[1] = f2bf(v0.y); r[2] = f2bf(v0.z); r[3] = f2bf(v0.w);
    r[4] = f2bf(v1.x); r[5] = f2bf(v1.y); r[6] = f2bf(v1.z); r[7] = f2bf(v1.w);
    const int j = gid >> 5, c5 = gid & 31;
    const int idx16 = (((j >> 4) * 8 + (c5 >> 2)) * 64) + (c5 & 3) * 16 + (j & 15);
    ((uint4*)zbf2)[idx16] = *(const uint4*)r;
    if (gid < BN) {                                       // cls_cnt pre-zeroed
        const int c = labels[gid];
        const int slot = atomicAdd(&cls_cnt[c], 1);
        if (slot < CAPI) cls_idx[c * CAPI + slot] = gid;
    }
}

// ------- kernel 1c: gather class members to row-major bf16 zcls -----------
// 100 blocks x 512 thr (8 waves); wave handles rows w, w+8, ... (zero-pad).
__global__ __launch_bounds__(512) void k_gather(const float* __restrict__ zf,
                                                const int* __restrict__ cls_cnt,
                                                const int* __restrict__ cls_idx,
                                                unsigned short* __restrict__ zcls) {
    const int c = blockIdx.x;
    const int w = threadIdx.x >> 6, lane = threadIdx.x & 63;
    const int n_c = min(cls_cnt[c], CAP);
    const int rows_p = ((n_c + 15) >> 4) << 4;
    for (int row = w; row < rows_p; row += 8) {
        unsigned int pk = 0;
        if (row < n_c) {
            const int g = cls_idx[c * CAPI + row];
            const float2 v = *(const float2*)(zf + (size_t)g * DD + lane * 2);
            pk = (unsigned)f2bf(v.x) | ((unsigned)f2bf(v.y) << 16);
        }
        *(unsigned int*)((char*)zcls + ((size_t)(c * CAP + row)) * 512 + lane * 4) = pk;
    }
}

// ------- kernel 2a: per-class sum_same + e-cache (runs before passA) ------
// Grid (100, 10) x 256 thr (4 waves). Block (c,t): rows [16t,16t+16) x all
// class cols; wave w takes col-tiles nj % 4 == w.
__global__ __launch_bounds__(256) void k_passB1(const unsigned short* __restrict__ zcls,
                                                const int* __restrict__ cls_cnt,
                                                unsigned short* __restrict__ emat,
                                                float* __restrict__ sums_g) {
    __shared__ float s16[16];
    const int c = blockIdx.x, t = blockIdx.y;
    const int n_c = min(cls_cnt[c], CAP);
    const int nt = (n_c + 15) >> 4;
    if (t >= nt) return;
    const int w = threadIdx.x >> 6, lane = threadIdx.x & 63;
    const int l15 = lane & 15, lk = lane >> 4;
    const char* zc = (const char*)zcls + (size_t)c * CAP * 512;

    if (threadIdx.x < 16) s16[threadIdx.x] = 0.f;
    __syncthreads();

    bf16x8 a[8];
    const char* ap = zc + (size_t)(t * 16 + l15) * 512 + lk * 16;
#pragma unroll
    for (int kf = 0; kf < 8; ++kf) a[kf] = *(const bf16x8*)(ap + kf * 64);

    float sp[4] = {};
    for (int nj = w; nj < nt; nj += 4) {
        const int colB = nj * 16 + l15;
        const char* bp = zc + (size_t)colB * 512 + lk * 16;
        bf16x8 b[8];
#pragma unroll
        for (int kf = 0; kf < 8; ++kf) b[kf] = *(const bf16x8*)(bp + kf * 64);
        f32x4 acc = {};
#pragma unroll
        for (int kf = 0; kf < 8; ++kf)
            acc = __builtin_amdgcn_mfma_f32_16x16x32_bf16(a[kf], b[kf], acc, 0, 0, 0);
        unsigned short ep[4];
#pragma unroll
        for (int rr = 0; rr < 4; ++rr) {
            const int i = t * 16 + lk * 4 + rr;
            const float e = exp2f(acc[rr] * K2E);         // same formula as passA
            ep[rr] = f2bf(e);
            sp[rr] += (colB < n_c && i != colB) ? e : 0.f;
        }
        uint2 uv;
        uv.x = (unsigned)ep[0] | ((unsigned)ep[1] << 16);
        uv.y = (unsigned)ep[2] | ((unsigned)ep[3] << 16);
        *(uint2*)&emat[((size_t)(c * CAP + colB)) * CAP + t * 16 + lk * 4] = uv;
    }
#pragma unroll
    for (int rr = 0; rr < 4; ++rr) {
        float v = sp[rr];
        v += __shfl_xor(v, 1, 64);
        v += __shfl_xor(v, 2, 64);
        v += __shfl_xor(v, 4, 64);
        v += __shfl_xor(v, 8, 64);
        if (l15 == 0) atomicAdd(&s16[lk * 4 + rr], v);
    }
    __syncthreads();
    if (threadIdx.x < 16)
        atomicAdd(&sums_g[c * CAP + t * 16 + threadIdx.x], s16[threadIdx.x]);
}

// ---------------- kernel 3: row sums of exp(z z^T / T), diag masked -------
// Grid 512 = 128 row-tiles(64 rows) x 4 col-quarters. 512 thr = 8 waves.
// Wave w streams col tiles [cq*128 + w*16, +16). No LDS staging, no barriers.
__global__ __launch_bounds__(512, 2) void k_passA(const char* __restrict__ zb2,
                                                  float* __restrict__ sn) {
    const int tid = threadIdx.x;
    const int w = tid >> 6, lane = tid & 63;
    const int l15 = lane & 15, lk = lane >> 4;
    const int rowbase = (blockIdx.x >> 2) * 64;
    const int cq = blockIdx.x & 3;
    const int jt0 = cq * 128 + w * 16;        // first global 16-col tile idx

    // A fragments: whole 64-row tile, full K, from fragment-major layout.
    const int rt0 = rowbase >> 4;
    bf16x8 a[4][8];
#pragma unroll
    for (int m = 0; m < 4; ++m) {
        const char* p = zb2 + ((size_t)(rt0 + m) * 8192) + lane * 16;
#pragma unroll
        for (int kf = 0; kf < 8; ++kf)
            a[m][kf] = *(const bf16x8*)(p + kf * 1024);
    }

    float snp[4][4] = {};
    bf16x8 b0[8], b1[8];

    auto loadB = [&](bf16x8 (&dst)[8], int jt) {
        const char* p = zb2 + ((size_t)jt * 8192) + lane * 16;
#pragma unroll
        for (int kf = 0; kf < 8; ++kf)
            dst[kf] = *(const bf16x8*)(p + kf * 1024);
    };
    auto computeTile = [&](bf16x8 (&bx)[8], int jt) {
        f32x4 acc[4] = {};
        __builtin_amdgcn_s_setprio(1);
#pragma unroll
        for (int kf = 0; kf < 8; ++kf)
#pragma unroll
            for (int m = 0; m < 4; ++m)
                acc[m] = __builtin_amdgcn_mfma_f32_16x16x32_bf16(a[m][kf], bx[kf], acc[m], 0, 0, 0);
        __builtin_amdgcn_s_setprio(0);
        const int jj = jt * 16 + l15;
#pragma unroll
        for (int m = 0; m < 4; ++m) {
            const int ig = rowbase + m * 16 + lk * 4;
#pragma unroll
            for (int rr = 0; rr < 4; ++rr) {
                float e = exp2f(acc[m][rr] * K2E);
                if (ig + rr == jj) e = 0.f;               // mask diagonal
                snp[m][rr] += e;
            }
        }
    };

    loadB(b0, jt0);
    for (int t = 0; t < 16; t += 2) {
        loadB(b1, jt0 + t + 1);
        computeTile(b0, jt0 + t);
        if (t + 2 < 16) loadB(b0, jt0 + t + 2);
        computeTile(b1, jt0 + t + 1);
    }

    // reduce across the 16 l15 lanes sharing each row; one atomic per row
#pragma unroll
    for (int m = 0; m < 4; ++m) {
#pragma unroll
        for (int rr = 0; rr < 4; ++rr) {
            float v = snp[m][rr];
            v += __shfl_xor(v, 1, 64);
            v += __shfl_xor(v, 2, 64);
            v += __shfl_xor(v, 4, 64);
            v += __shfl_xor(v, 8, 64);
            if (l15 == 0)
                atomicAdd(&sn[rowbase + m * 16 + lk * 4 + rr], v);
        }
    }
}

// ------- kernel 2b: pair losses from e-cache ------------------------------
// Grid (100, 10) x 256 thr (4 waves). Block (c,t): rows [16t,16t+16).
__global__ __launch_bounds__(256) void k_passB2(const float* __restrict__ sn,
                                                const float* __restrict__ sums_g,
                                                const int* __restrict__ cls_cnt,
                                                const int* __restrict__ cls_idx,
                                                const unsigned short* __restrict__ emat,
                                                float* __restrict__ gacc) {
    __shared__ float snl16[16];
    __shared__ float ls16[16];
    const int c = blockIdx.x, t = blockIdx.y;
    const int n_c = min(cls_cnt[c], CAP);
    const int nt = (n_c + 15) >> 4;
    if (t >= nt || n_c <= 1) return;
    const int w = threadIdx.x >> 6, lane = threadIdx.x & 63;
    const int l15 = lane & 15, lk = lane >> 4;

    if (threadIdx.x < 16) {
        const int i = t * 16 + threadIdx.x;
        float v = 0.f;
        if (i < n_c) {
            const int g = cls_idx[c * CAPI + i];
            v = sn[g] - sums_g[c * CAP + i];
        }
        snl16[threadIdx.x] = v;
        ls16[threadIdx.x] = 0.f;
    }
    __syncthreads();

    float sneg[4];
#pragma unroll
    for (int rr = 0; rr < 4; ++rr) sneg[rr] = snl16[lk * 4 + rr];

    float sp[4] = {};
    for (int nj = w; nj < nt; nj += 4) {
        const int colB = nj * 16 + l15;
        const uint2 pk = *(const uint2*)&emat[((size_t)(c * CAP + colB)) * CAP + t * 16 + lk * 4];
        float ev[4];
        ev[0] = bf2f((unsigned short)(pk.x & 0xffff));
        ev[1] = bf2f((unsigned short)(pk.x >> 16));
        ev[2] = bf2f((unsigned short)(pk.y & 0xffff));
        ev[3] = bf2f((unsigned short)(pk.y >> 16));
#pragma unroll
        for (int rr = 0; rr < 4; ++rr) {
            const int i = t * 16 + lk * 4 + rr;
            const float tl = log1pf(sneg[rr] / ev[rr]);
            sp[rr] += (colB < n_c && i != colB) ? tl : 0.f;
        }
    }
#pragma unroll
    for (int rr = 0; rr < 4; ++rr) {
        float v = sp[rr];
        v += __shfl_xor(v, 1, 64);
        v += __shfl_xor(v, 2, 64);
        v += __shfl_xor(v, 4, 64);
        v += __shfl_xor(v, 8, 64);
        if (l15 == 0) {
            const int i = t * 16 + lk * 4 + rr;
            if (i < n_c) atomicAdd(&ls16[lk * 4 + rr], v);
        }
    }
    __syncthreads();
    if (threadIdx.x == 0) {
        float L = 0.f;
        for (int i = 0; i < 16; ++i) L += ls16[i];
        atomicAdd(&gacc[0], L / (float)(n_c - 1));
        if (t == 0) atomicAdd(&gacc[1], (float)n_c);
    }
}

// ---------------- kernel 4: final scalar ----------------------------------
__global__ void k_final(const float* __restrict__ gacc, float* __restrict__ out) {
    if (threadIdx.x == 0) {
        const float L = gacc[0], V = gacc[1];
        out[0] = (V > 0.f) ? L / fmaxf(V, 1.f) : 0.f;
    }
}

extern "C" void kernel_launch(void* const* d_in, const int* in_sizes, int n_in,
                              void* d_out, int out_size, void* d_ws, size_t ws_size,
                              hipStream_t stream) {
    const float* z      = (const float*)d_in[0];
    const int*   labels = (const int*)d_in[1];
    float* out = (float*)d_out;

    char* ws = (char*)d_ws;
    // zbf2 4MB | [sn 32KB | cls_cnt 1KB | gacc 256B | sums_g 64KB] (memset) |
    // cls_idx 100KB | zcls 8.2MB | emat 5.12MB
    unsigned short* zbf2 = (unsigned short*)ws;
    size_t off = (size_t)BN * DD * sizeof(unsigned short);
    char* mz = ws + off;                          // memset region start
    float* sn      = (float*)(ws + off);  off += BN * sizeof(float);
    int*   cls_cnt = (int*)(ws + off);    off += 1024;
    float* gacc    = (float*)(ws + off);  off += 256;
    float* sums_g  = (float*)(ws + off);  off += 100 * CAP * sizeof(float);
    size_t mz_bytes = (size_t)((ws + off) - mz);
    int*   cls_idx = (int*)(ws + off);    off += 100 * CAPI * sizeof(int);
    unsigned short* zcls = (unsigned short*)(ws + off); off += (size_t)100 * CAP * DD * 2;
    unsigned short* emat = (unsigned short*)(ws + off); off += (size_t)100 * CAP * CAP * 2;

    hipMemsetAsync(mz, 0, mz_bytes, stream);
    k_prep  <<<1024, 256, 0, stream>>>(z, zbf2, labels, cls_cnt, cls_idx);
    k_gather<<<100, 512, 0, stream>>>(z, cls_cnt, cls_idx, zcls);
    k_passB1<<<dim3(100, 10), 256, 0, stream>>>(zcls, cls_cnt, emat, sums_g);
    k_passA <<<512, 512, 0, stream>>>((const char*)zbf2, sn);
    k_passB2<<<dim3(100, 10), 256, 0, stream>>>(sn, sums_g, cls_cnt, cls_idx, emat, gacc);
    k_final <<<1, 64, 0, stream>>>(gacc, out);
}

// Round 14
// 87.050 us; speedup vs baseline: 3.0799x; 1.1892x over previous
//
#include <hip/hip_runtime.h>
#include <hip/hip_bf16.h>

// Supervised contrastive loss, B=8192, D=256, T=0.07, 100 classes.
//   memset: zero cls_cnt + gacc + done (1280 B)
//   prep:   z f32 -> bf16 row-major zbf + fused class bucketing
//   passA:  row sums of exp(z@z^T/T), diag masked (R8 structure, measured
//           43.5us): 256 blocks = 64 row-tiles x 4 col-quarters, 8 waves
//           (2 wr x 4 wc, m=4), A regs via LDS bounce, 128-col dbuf LDS
//           staging via global_load_lds w16 + XOR swizzle. Per-block
//           sn_part stores (no atomics).
//   passB:  per class (100 blocks x 8 waves), single kernel:
//           async-gather members to LDS; pass1 = flat (mi,nj) tile-pair
//           distribution over all 8 waves, MFMA (bitwise-equal d to passA:
//           same bf16 bits, same kf order) -> e-cache in LDS dmat + row
//           sums; sum_neg = sum_all - sum_same; pass2 = log1p from dmat
//           (no second MFMA); atomics into gacc; LAST block (done counter)
//           writes out[0]. No k_final dispatch.

#define BN 8192
#define DD 256
#define INV_T (1.0f / 0.07f)
#define CAPI 256
#define CAP 160
#define IPAD 164

typedef __attribute__((ext_vector_type(8))) __bf16 bf16x8;
typedef __attribute__((ext_vector_type(4))) float f32x4;

typedef const __attribute__((address_space(1))) void gas_void;
typedef __attribute__((address_space(3))) void las_void;

static __device__ __forceinline__ void gld_lds16(const void* g, void* l) {
    __builtin_amdgcn_global_load_lds((gas_void*)g, (las_void*)l, 16, 0, 0);
}

static __device__ __forceinline__ unsigned short f2bf(float f) {
    unsigned int u = __builtin_bit_cast(unsigned int, f);
    u = (u + 0x7FFFu + ((u >> 16) & 1u)) >> 16;   // RNE, inputs finite
    return (unsigned short)u;
}
static __device__ __forceinline__ float bf2f(unsigned short s) {
    unsigned int u = (unsigned int)s << 16;
    return __builtin_bit_cast(float, u);
}

// ------- kernel 1: f32 -> bf16 row-major zbf + fused class bucketing ------
__global__ __launch_bounds__(256) void k_prep(const float* __restrict__ z,
                                              unsigned short* __restrict__ zbf,
                                              const int* __restrict__ labels,
                                              int* __restrict__ cls_cnt,
                                              int* __restrict__ cls_idx) {
    const int gid = blockIdx.x * 256 + threadIdx.x;       // 262144 threads
    const float4* z4 = (const float4*)z;
    float4 v0 = z4[gid * 2 + 0];
    float4 v1 = z4[gid * 2 + 1];
    unsigned short r[8];
    r[0] = f2bf(v0.x); r[1] = f2bf(v0.y); r[2] = f2bf(v0.z); r[3] = f2bf(v0.w);
    r[4] = f2bf(v1.x); r[5] = f2bf(v1.y); r[6] = f2bf(v1.z); r[7] = f2bf(v1.w);
    ((uint4*)zbf)[gid] = *(const uint4*)r;
    if (gid < BN) {                                       // cls_cnt pre-zeroed
        const int c = labels[gid];
        const int slot = atomicAdd(&cls_cnt[c], 1);
        if (slot < CAPI) cls_idx[c * CAPI + slot] = gid;
    }
}

// ---------------- kernel 2: row sums of exp(z z^T / T), diag masked -------
// Grid 256 = 64 row-tiles x 4 col-quarters. 512 thr = 8 waves (2 wr x 4 wc).
// Block: 128 rows x 2048 cols; per step 128 cols staged in LDS (dbuf).
__global__ __launch_bounds__(512, 2) void k_passA(const unsigned short* __restrict__ zbf,
                                                  float* __restrict__ sn_part) {
    __shared__ char Bb[2][65536];             // [128 cols][512 B], swizzled
    __shared__ float sn_lds[128];

    const int tid = threadIdx.x;
    const int by = blockIdx.x >> 2;
    const int cq = blockIdx.x & 3;
    const int rowbase = by * 128;
    const int colbase = cq * 2048;
    const char* zb = (const char*)zbf;

    auto stage = [&](int buf, int ns) {       // 128 cols x 512 B, swizzled
        const char* gB = zb + ((size_t)(colbase + ns * 128)) * 512;
        char* lb = Bb[buf];
#pragma unroll
        for (int qq = 0; qq < 8; ++qq) {
            const int s = (qq * 512 + tid) * 16;
            const int col = s >> 9, koff = s & 511;
            const int ksrc = koff ^ ((col & 7) << 4);   // pre-swizzled source
            gld_lds16(gB + (size_t)col * 512 + ksrc, lb + s);
        }
    };

    const int w = tid >> 6, lane = tid & 63;
    const int l15 = lane & 15, lk = lane >> 4;
    const int wr = w & 1, wc = w >> 1;        // 2 row-groups x 4 col-groups

    // ---- A tile via LDS bounce: stage rows once, read frags to regs ----
    {
        const char* gA = zb + (size_t)rowbase * 512;
        char* lb = Bb[0];
#pragma unroll
        for (int qq = 0; qq < 8; ++qq) {
            const int s = (qq * 512 + tid) * 16;
            const int row = s >> 9, koff = s & 511;
            const int ksrc = koff ^ ((row & 7) << 4);
            gld_lds16(gA + (size_t)row * 512 + ksrc, lb + s);
        }
    }
    __syncthreads();                          // A staged (barrier drains vmcnt)

    bf16x8 a[4][8];
#pragma unroll
    for (int m = 0; m < 4; ++m) {
        const int row = wr * 64 + m * 16 + l15;
        const int sw = (row & 7) << 4;
#pragma unroll
        for (int kf = 0; kf < 8; ++kf)
            a[m][kf] = *(const bf16x8*)(Bb[0] + row * 512 + ((lk * 16 + kf * 64) ^ sw));
    }
    int iglob[4][4];
#pragma unroll
    for (int m = 0; m < 4; ++m)
#pragma unroll
        for (int rr = 0; rr < 4; ++rr)
            iglob[m][rr] = rowbase + wr * 64 + m * 16 + lk * 4 + rr;

    if (tid < 128) sn_lds[tid] = 0.f;
    float snp[4][4] = {};

    __syncthreads();                          // A-frag reads complete
    stage(0, 0);
    __syncthreads();                          // buf0 ready

    for (int ns = 0; ns < 16; ++ns) {
        const int buf = ns & 1;
        if (ns < 15) stage(buf ^ 1, ns + 1);
        const char* bp0 = Bb[buf];
#pragma unroll
        for (int n = 0; n < 2; ++n) {
            const int colL = wc * 32 + n * 16 + l15;
            const char* bp = bp0 + (size_t)colL * 512;
            const int sw = (colL & 7) << 4;
            bf16x8 b[8];
#pragma unroll
            for (int kf = 0; kf < 8; ++kf)
                b[kf] = *(const bf16x8*)(bp + ((lk * 16 + kf * 64) ^ sw));
            const int jj = colbase + ns * 128 + colL;
#pragma unroll
            for (int m = 0; m < 4; ++m) {
                f32x4 acc = {};
#pragma unroll
                for (int kf = 0; kf < 8; ++kf)
                    acc = __builtin_amdgcn_mfma_f32_16x16x32_bf16(a[m][kf], b[kf], acc, 0, 0, 0);
#pragma unroll
                for (int rr = 0; rr < 4; ++rr) {
                    float e = __expf(acc[rr] * INV_T);
                    if (iglob[m][rr] == jj) e = 0.f;     // mask diagonal
                    snp[m][rr] += e;
                }
            }
        }
        __syncthreads();
    }

    // reduce across the 16 l15 lanes sharing each row, combine wc-groups in LDS
#pragma unroll
    for (int m = 0; m < 4; ++m) {
#pragma unroll
        for (int rr = 0; rr < 4; ++rr) {
            float v = snp[m][rr];
            v += __shfl_xor(v, 1, 64);
            v += __shfl_xor(v, 2, 64);
            v += __shfl_xor(v, 4, 64);
            v += __shfl_xor(v, 8, 64);
            if (l15 == 0)
                atomicAdd(&sn_lds[wr * 64 + m * 16 + lk * 4 + rr], v);
        }
    }
    __syncthreads();
    if (tid < 128)
        sn_part[(size_t)cq * BN + rowbase + tid] = sn_lds[tid];
}

// ---------------- kernel 3: per-class positive pairs + final --------------
// 100 blocks x 512 thr (8 waves). Flat (mi,nj) tile-pair distribution,
// e-cache in dmat; last block writes out[0].
__global__ __launch_bounds__(512) void k_passB(const unsigned short* __restrict__ zbf,
                                               const float* __restrict__ sn_part,
                                               const int* __restrict__ cls_cnt,
                                               const int* __restrict__ cls_idx,
                                               float* __restrict__ gacc,
                                               int* __restrict__ done,
                                               float* __restrict__ out) {
    __shared__ char Zc[CAP * 512];             // swizzled [row][512 B]
    __shared__ unsigned short dmat[CAP * IPAD];// col-major e cache [j][iPad]
    __shared__ int glist[CAP];
    __shared__ float sums[CAP];
    __shared__ float snl[CAP];
    __shared__ float blkL;

    const int c = blockIdx.x;
    const int tid = threadIdx.x;
    const int w = tid >> 6, lane = tid & 63;
    const int l15 = lane & 15, lk = lane >> 4;
    const char* zb = (const char*)zbf;

    const int n_c = min(cls_cnt[c], CAP);
    const int nt = (n_c + 15) >> 4;
    const int rows_p = nt * 16;
    const int NT2 = nt * nt;

    if (tid < CAP) {
        glist[tid] = (tid < n_c) ? cls_idx[c * CAPI + tid] : 0;
        sums[tid] = 0.f;
    }
    if (tid == 0) blkL = 0.f;
    __syncthreads();

    // async gather: one wave-instr moves 2 rows (64 lanes x 16B), swizzled src
    for (int e2 = w * 2; e2 < rows_p; e2 += 16) {
        const int row = e2 + (lane >> 5);
        const int cb = (lane & 31) * 16;
        gld_lds16(zb + (size_t)glist[row] * 512 + (cb ^ ((row & 7) << 4)),
                  (char*)Zc + e2 * 512);
    }
    __syncthreads();                           // vmcnt drained by barrier

    // ---- pass 1: flat tile-pairs; sum_same + e-cache ----
    for (int wi = w; wi < NT2; wi += 8) {
        const int mi = wi / nt, nj = wi - mi * nt;
        const int rowA = mi * 16 + l15;
        const int swa = (rowA & 7) << 4;
        bf16x8 a[8];
#pragma unroll
        for (int kf = 0; kf < 8; ++kf)
            a[kf] = *(const bf16x8*)(Zc + rowA * 512 + ((lk * 16 + kf * 64) ^ swa));
        const int colB = nj * 16 + l15;
        const int swb = (colB & 7) << 4;
        bf16x8 b[8];
#pragma unroll
        for (int kf = 0; kf < 8; ++kf)
            b[kf] = *(const bf16x8*)(Zc + colB * 512 + ((lk * 16 + kf * 64) ^ swb));
        f32x4 acc = {};
#pragma unroll
        for (int kf = 0; kf < 8; ++kf)
            acc = __builtin_amdgcn_mfma_f32_16x16x32_bf16(a[kf], b[kf], acc, 0, 0, 0);
        unsigned short ep[4];
        float spv[4];
#pragma unroll
        for (int rr = 0; rr < 4; ++rr) {
            const int i = mi * 16 + lk * 4 + rr;
            const float e = __expf(acc[rr] * INV_T);
            ep[rr] = f2bf(e);
            spv[rr] = (colB < n_c && i != colB) ? e : 0.f;
        }
        uint2 uv;
        uv.x = (unsigned)ep[0] | ((unsigned)ep[1] << 16);
        uv.y = (unsigned)ep[2] | ((unsigned)ep[3] << 16);
        *(uint2*)&dmat[colB * IPAD + mi * 16 + lk * 4] = uv;
#pragma unroll
        for (int rr = 0; rr < 4; ++rr) {
            float v = spv[rr];
            v += __shfl_xor(v, 1, 64);
            v += __shfl_xor(v, 2, 64);
            v += __shfl_xor(v, 4, 64);
            v += __shfl_xor(v, 8, 64);
            if (l15 == 0) atomicAdd(&sums[mi * 16 + lk * 4 + rr], v);
        }
    }
    __syncthreads();
    if (tid < CAP) {
        float v = 0.f;
        if (tid < n_c) {
            const int g = glist[tid];
            v = sn_part[g] + sn_part[BN + g] + sn_part[2 * BN + g]
              + sn_part[3 * BN + g] - sums[tid];
        }
        snl[tid] = v;
    }
    __syncthreads();

    // ---- pass 2: pair losses from the e-cache (no MFMA) ----
    for (int wi = w; wi < NT2; wi += 8) {
        const int mi = wi / nt, nj = wi - mi * nt;
        const int colB = nj * 16 + l15;
        float sneg[4];
#pragma unroll
        for (int rr = 0; rr < 4; ++rr) {
            const int i = mi * 16 + lk * 4 + rr;
            sneg[rr] = (i < n_c) ? snl[i] : 0.f;
        }
        const uint2 pk = *(const uint2*)&dmat[colB * IPAD + mi * 16 + lk * 4];
        float ev[4];
        ev[0] = bf2f((unsigned short)(pk.x & 0xffff));
        ev[1] = bf2f((unsigned short)(pk.x >> 16));
        ev[2] = bf2f((unsigned short)(pk.y & 0xffff));
        ev[3] = bf2f((unsigned short)(pk.y >> 16));
        float spv[4];
#pragma unroll
        for (int rr = 0; rr < 4; ++rr) {
            const int i = mi * 16 + lk * 4 + rr;
            const float t = log1pf(sneg[rr] / ev[rr]);
            spv[rr] = (colB < n_c && i < n_c && i != colB) ? t : 0.f;
        }
#pragma unroll
        for (int rr = 0; rr < 4; ++rr) {
            float v = spv[rr];
            v += __shfl_xor(v, 1, 64);
            v += __shfl_xor(v, 2, 64);
            v += __shfl_xor(v, 4, 64);
            v += __shfl_xor(v, 8, 64);
            if (l15 == 0) atomicAdd(&blkL, v);
        }
    }
    __syncthreads();

    if (tid == 0) {
        if (n_c > 1) {
            atomicAdd(&gacc[0], blkL / (float)(n_c - 1));
            atomicAdd(&gacc[1], (float)n_c);
        }
        __threadfence();
        const int old = atomicAdd(done, 1);
        if (old == 99) {                       // last block finalizes
            const float L = atomicAdd(&gacc[0], 0.f);
            const float V = atomicAdd(&gacc[1], 0.f);
            out[0] = (V > 0.f) ? L / fmaxf(V, 1.f) : 0.f;
        }
    }
}

extern "C" void kernel_launch(void* const* d_in, const int* in_sizes, int n_in,
                              void* d_out, int out_size, void* d_ws, size_t ws_size,
                              hipStream_t stream) {
    const float* z      = (const float*)d_in[0];
    const int*   labels = (const int*)d_in[1];
    float* out = (float*)d_out;

    char* ws = (char*)d_ws;
    // zbf 4MB | sn_part 4xBN f32 | [cls_cnt 1KB | gacc 8B | done 4B | pad]
    // (memset 1280B) | cls_idx 100KB
    unsigned short* zbf = (unsigned short*)ws;
    size_t off = (size_t)BN * DD * sizeof(unsigned short);
    float* sn_part = (float*)(ws + off);  off += 4 * BN * sizeof(float);
    char*  mz      = ws + off;
    int*   cls_cnt = (int*)(ws + off);    off += 1024;
    float* gacc    = (float*)(ws + off);  off += 8;
    int*   done    = (int*)(ws + off);    off += 4;
    off += 244;                                           // pad to 1280
    int*   cls_idx = (int*)(ws + off);    off += 100 * CAPI * sizeof(int);

    hipMemsetAsync(mz, 0, 1280, stream);
    k_prep  <<<1024, 256, 0, stream>>>(z, zbf, labels, cls_cnt, cls_idx);
    k_passA <<<256, 512, 0, stream>>>(zbf, sn_part);
    k_passB <<<100, 512, 0, stream>>>(zbf, sn_part, cls_cnt, cls_idx, gacc, done, out);
}